// Round 3
// baseline (171.895 us; speedup 1.0000x reference)
//
#include <hip/hip_runtime.h>

// ComplexMixture: B=32, S=8192, D=64, fp32 in/out.
// out_real = (R^T R + I^T I)/S ; out_imag = (R^T I - (R^T I)^T)/S
// R3: stage raw fp32 tiles via global_load_lds(width=16) -> guaranteed MLP;
// bf16 convert at LDS->frag read; Gram-symmetric wave split (10 frags+10 MFMA
// per k-step instead of 16+12); split-K partials in ws + reduce kernel.

#define BATCH 32
#define SEQ   8192
#define DD    64
#define BK    64

typedef __bf16 bf16x8 __attribute__((ext_vector_type(8)));
typedef float  f32x16 __attribute__((ext_vector_type(16)));

#define GLD_LDS16(gp, lp) \
  __builtin_amdgcn_global_load_lds( \
      (const __attribute__((address_space(1))) void*)(gp), \
      (__attribute__((address_space(3))) void*)(lp), 16, 0, 0)

__device__ __forceinline__ unsigned bf16pk(float a, float b) {
  unsigned ua = __builtin_bit_cast(unsigned, a);
  unsigned ub = __builtin_bit_cast(unsigned, b);
  ua = (ua + 0x7fffu + ((ua >> 16) & 1u)) >> 16;   // RNE to bf16
  ub = (ub + 0x7fffu + ((ub >> 16) & 1u)) >> 16;
  return (ua & 0xffffu) | (ub << 16);
}

// Read 8 floats at stride 64 (one MFMA fragment's k-run), pack to bf16x8.
__device__ __forceinline__ bf16x8 ldsfrag(const float* p) {
  float f0 = p[0*64], f1 = p[1*64], f2 = p[2*64], f3 = p[3*64];
  float f4 = p[4*64], f5 = p[5*64], f6 = p[6*64], f7 = p[7*64];
  uint4 q;
  q.x = bf16pk(f0, f1); q.y = bf16pk(f2, f3);
  q.z = bf16pk(f4, f5); q.w = bf16pk(f6, f7);
  return __builtin_bit_cast(bf16x8, q);
}

#define MFMA(a, b, c) __builtin_amdgcn_mfma_f32_32x32x16_bf16((a), (b), (c), 0, 0, 0)

// LDS: staging = fp32 tiles R[64][64] ++ I[64][64] (8192 floats);
// epilogue reuse = two 64x65 padded float mats (8320 floats). Max 8320.
template<int CHUNKS>
__global__ __launch_bounds__(256, 4) void gram_partial(
    const float* __restrict__ R, const float* __restrict__ I,
    float* __restrict__ ws)
{
  constexpr int SCHUNK = SEQ / CHUNKS;
  constexpr int NIT    = SCHUNK / BK;
  __shared__ float lds[8320];
  float* ldsR = lds;
  float* ldsI = lds + 4096;

  const int tid  = threadIdx.x;
  const int wave = tid >> 6;
  const int lane = tid & 63;
  const int l31  = lane & 31;
  const int lhi  = lane >> 5;
  const int b = blockIdx.x & 31;
  const int c = blockIdx.x >> 5;
  const float* Rb = R + (size_t)b * (SEQ * DD);
  const float* Ib = I + (size_t)b * (SEQ * DD);

  f32x16 acc0 = {};   // w0:S(0,0)  w1:S(0,32)  w2:M(32,0)  w3:S(32,32)
  f32x16 acc1 = {};   // w0:M(0,0)  w1:unused   w2:M(0,32)  w3:M(32,32)

  const int chunk0 = c * SCHUNK;

  for (int it = 0; it < NIT; ++it) {
    const float* gR = Rb + (size_t)(chunk0 + it * BK) * DD;
    const float* gI = Ib + (size_t)(chunk0 + it * BK) * DD;
    // ---- stage: 8 async direct-to-LDS copies per wave, no VGPR round trip ----
    #pragma unroll
    for (int t = 0; t < 4; ++t) {
      const int row0 = wave * 16 + t * 4;             // 4 rows = 1 KB per instr
      GLD_LDS16(gR + row0 * 64 + lane * 4, &ldsR[row0 * 64]);
      GLD_LDS16(gI + row0 * 64 + lane * 4, &ldsI[row0 * 64]);
    }
    __syncthreads();   // compiler emits vmcnt(0) drain here
    // ---- compute: 4 k-steps of 16; Gram-symmetric wave roles ----
    #pragma unroll
    for (int ks = 0; ks < 4; ++ks) {
      const int kb = (ks * 16 + lhi * 8) * 64 + l31;
      const float* pR = &ldsR[kb];
      const float* pI = &ldsI[kb];
      if (wave == 0) {
        bf16x8 r0 = ldsfrag(pR), i0 = ldsfrag(pI);
        acc0 = MFMA(r0, r0, acc0);
        acc0 = MFMA(i0, i0, acc0);
        acc1 = MFMA(r0, i0, acc1);
      } else if (wave == 1) {
        bf16x8 r0 = ldsfrag(pR), r32 = ldsfrag(pR + 32);
        bf16x8 i0 = ldsfrag(pI), i32 = ldsfrag(pI + 32);
        acc0 = MFMA(r0, r32, acc0);      // S(0,32) = rr part
        acc0 = MFMA(i0, i32, acc0);      //         + ii part
      } else if (wave == 2) {
        bf16x8 r0 = ldsfrag(pR), r32 = ldsfrag(pR + 32);
        bf16x8 i0 = ldsfrag(pI), i32 = ldsfrag(pI + 32);
        acc0 = MFMA(r32, i0, acc0);      // M(32,0)
        acc1 = MFMA(r0, i32, acc1);      // M(0,32)
      } else {
        bf16x8 r32 = ldsfrag(pR + 32), i32 = ldsfrag(pI + 32);
        acc0 = MFMA(r32, r32, acc0);
        acc0 = MFMA(i32, i32, acc0);
        acc1 = MFMA(r32, i32, acc1);
      }
    }
    __syncthreads();
  }

  // ---- epilogue: assemble full 64x64 S and M in padded LDS, emit partials ----
  float* ldsS = lds;          // 64 x 65
  float* ldsM = lds + 4160;   // 64 x 65
  const int jj = l31;
  #pragma unroll
  for (int r = 0; r < 16; ++r) {
    const int ii = (r & 3) + 8 * (r >> 2) + 4 * lhi;   // within-tile row
    if (wave == 0) {
      ldsS[ii * 65 + jj]               = acc0[r];
      ldsM[ii * 65 + jj]               = acc1[r];
    } else if (wave == 1) {
      ldsS[ii * 65 + 32 + jj]          = acc0[r];
    } else if (wave == 2) {
      ldsM[(32 + ii) * 65 + jj]        = acc0[r];
      ldsM[ii * 65 + 32 + jj]          = acc1[r];
    } else {
      ldsS[(32 + ii) * 65 + 32 + jj]   = acc0[r];
      ldsM[(32 + ii) * 65 + 32 + jj]   = acc1[r];
    }
  }
  __syncthreads();
  float* wsS = ws + ((size_t)(c * 32 + b) * 2) * 4096;
  float* wsM = wsS + 4096;
  #pragma unroll
  for (int k = 0; k < 16; ++k) {
    const int e = tid + 256 * k;
    const int i = e >> 6, j = e & 63;
    const float sv = (i >= 32 && j < 32) ? ldsS[j * 65 + i] : ldsS[i * 65 + j];
    wsS[e] = sv;
    wsM[e] = ldsM[i * 65 + j] - ldsM[j * 65 + i];
  }
}

// Sum CHUNKS chunk-partials, scale by 1/S. out = real[32][64][64] ++ imag[...].
template<int CHUNKS>
__global__ __launch_bounds__(256) void gram_reduce(
    const float4* __restrict__ ws, float4* __restrict__ out)
{
  const int o = blockIdx.x * 256 + threadIdx.x;   // 65536 float4s
  const int kind = o >> 15;
  const int rem  = o & 32767;
  const int b    = rem >> 10;
  const int e    = rem & 1023;
  const float inv = 1.0f / (float)SEQ;
  float sx = 0.f, sy = 0.f, sz = 0.f, sw = 0.f;
  #pragma unroll
  for (int c = 0; c < CHUNKS; ++c) {
    float4 v = ws[((size_t)(c * 32 + b) * 2 + kind) * 1024 + e];
    sx += v.x; sy += v.y; sz += v.z; sw += v.w;
  }
  float4 r; r.x = sx * inv; r.y = sy * inv; r.z = sz * inv; r.w = sw * inv;
  out[o] = r;
}

extern "C" void kernel_launch(void* const* d_in, const int* in_sizes, int n_in,
                              void* d_out, int out_size, void* d_ws, size_t ws_size,
                              hipStream_t stream) {
  const float* R = (const float*)d_in[0];
  const float* I = (const float*)d_in[1];
  float* out = (float*)d_out;
  float* ws  = (float*)d_ws;

  const size_t need32 = (size_t)32 * 32 * 2 * 4096 * 4;   // 33.6 MB
  if (ws_size >= need32) {
    gram_partial<32><<<BATCH * 32, 256, 0, stream>>>(R, I, ws);
    gram_reduce<32><<<256, 256, 0, stream>>>((const float4*)ws, (float4*)out);
  } else {
    gram_partial<16><<<BATCH * 16, 256, 0, stream>>>(R, I, ws);
    gram_reduce<16><<<256, 256, 0, stream>>>((const float4*)ws, (float4*)out);
  }
}

// Round 4
// 168.285 us; speedup vs baseline: 1.0214x; 1.0214x over previous
//
#include <hip/hip_runtime.h>

// ComplexMixture: B=32, S=8192, D=64, fp32 in/out.
// out_real = (R^T R + I^T I)/S ; out_imag = (R^T I - (R^T I)^T)/S
// R4: barrier-free main loop. MFMA fragments loaded DIRECTLY from global
// (coalesced: lanes = consecutive d), bf16-packed in regs, software-pipelined
// one step ahead. Wave roles split the 7 output tiles; LDS only in epilogue.

#define BATCH 32
#define SEQ   8192
#define DD    64

typedef __bf16 bf16x8 __attribute__((ext_vector_type(8)));
typedef float  f32x16 __attribute__((ext_vector_type(16)));

__device__ __forceinline__ unsigned bf16pk(float a, float b) {
  unsigned ua = __builtin_bit_cast(unsigned, a);
  unsigned ub = __builtin_bit_cast(unsigned, b);
  ua = (ua + 0x7fffu + ((ua >> 16) & 1u)) >> 16;   // RNE to bf16
  ub = (ub + 0x7fffu + ((ub >> 16) & 1u)) >> 16;
  return (ua & 0xffffu) | (ub << 16);
}

__device__ __forceinline__ bf16x8 pack8(const float* f) {
  uint4 q;
  q.x = bf16pk(f[0], f[1]); q.y = bf16pk(f[2], f[3]);
  q.z = bf16pk(f[4], f[5]); q.w = bf16pk(f[6], f[7]);
  return __builtin_bit_cast(bf16x8, q);
}

#define MFMA(a, b, c) __builtin_amdgcn_mfma_f32_32x32x16_bf16((a), (b), (c), 0, 0, 0)

// Wave roles (7 output tiles, S = rr+ii symmetric, M = ri):
//  w0: acc0 = S(0,0)   [2 mfma], acc1 = M(0,0)   [1 mfma]   needs r0,i0
//  w1: acc0 = S(0,32)  [2],      acc1 = M(0,32)  [1]        needs all 4
//  w2: acc0 = M(32,0)  [1],      acc1 = M(32,32) [1]        needs r32,i0,i32
//  w3: acc0 = S(32,32) [2]                                  needs r32,i32
template<int CHUNKS>
__global__ __launch_bounds__(256, 4) void gram_partial(
    const float* __restrict__ R, const float* __restrict__ I,
    float* __restrict__ ws)
{
  constexpr int SCHUNK = SEQ / CHUNKS;
  constexpr int NSTEP  = SCHUNK / 16;   // k16 steps per wave
  __shared__ float lds[2 * 64 * 65];    // epilogue only (33.3 KB)

  const int tid  = threadIdx.x;
  const int wave = tid >> 6;
  const int lane = tid & 63;
  const int l31  = lane & 31;
  const int lhi  = lane >> 5;
  const int b = blockIdx.x & 31;
  const int c = blockIdx.x >> 5;

  const bool nR0  = (wave <= 1);
  const bool nR32 = (wave >= 1);
  const bool nI0  = (wave <= 2);
  const bool nI32 = (wave >= 1);

  // lane element for step ks, reg j:  X[c*SCHUNK + ks*16 + lhi*8 + j][n + l31]
  const size_t base0 = (size_t)b * (SEQ * DD) + (size_t)(c * SCHUNK + lhi * 8) * DD + l31;
  const float* pR = R + base0;
  const float* pI = I + base0;

  f32x16 acc0 = {}, acc1 = {};
  float cur[4][8], nxt[4][8];

  auto LOADSTEP = [&](float (&dst)[4][8], int ks) {
    const float* r = pR + (size_t)ks * (16 * DD);
    const float* i = pI + (size_t)ks * (16 * DD);
    #pragma unroll
    for (int j = 0; j < 8; ++j) {
      if (nR0)  dst[0][j] = r[j * DD];
      if (nR32) dst[1][j] = r[j * DD + 32];
      if (nI0)  dst[2][j] = i[j * DD];
      if (nI32) dst[3][j] = i[j * DD + 32];
    }
  };

  auto COMPUTE = [&](float (&fr)[4][8]) {
    if (wave == 0) {
      bf16x8 r0 = pack8(fr[0]), i0 = pack8(fr[2]);
      acc0 = MFMA(r0, r0, acc0);
      acc0 = MFMA(i0, i0, acc0);
      acc1 = MFMA(r0, i0, acc1);
    } else if (wave == 1) {
      bf16x8 r0 = pack8(fr[0]), r32 = pack8(fr[1]);
      bf16x8 i0 = pack8(fr[2]), i32 = pack8(fr[3]);
      acc0 = MFMA(r0, r32, acc0);
      acc0 = MFMA(i0, i32, acc0);
      acc1 = MFMA(r0, i32, acc1);
    } else if (wave == 2) {
      bf16x8 r32 = pack8(fr[1]), i0 = pack8(fr[2]), i32 = pack8(fr[3]);
      acc0 = MFMA(r32, i0, acc0);
      acc1 = MFMA(r32, i32, acc1);
    } else {
      bf16x8 r32 = pack8(fr[1]), i32 = pack8(fr[3]);
      acc0 = MFMA(r32, r32, acc0);
      acc0 = MFMA(i32, i32, acc0);
    }
  };

  LOADSTEP(cur, 0);
  for (int ks = 0; ks < NSTEP; ks += 2) {
    LOADSTEP(nxt, ks + 1);
    COMPUTE(cur);
    if (ks + 2 < NSTEP) LOADSTEP(cur, ks + 2);
    COMPUTE(nxt);
  }

  // ---- epilogue: assemble S and M in padded LDS, emit block partials ----
  float* ldsS = lds;          // 64 x 65
  float* ldsM = lds + 4160;   // 64 x 65
  const int jj = l31;
  #pragma unroll
  for (int r = 0; r < 16; ++r) {
    const int ii = (r & 3) + 8 * (r >> 2) + 4 * lhi;
    if (wave == 0) {
      ldsS[ii * 65 + jj]              = acc0[r];
      ldsM[ii * 65 + jj]              = acc1[r];
    } else if (wave == 1) {
      ldsS[ii * 65 + 32 + jj]         = acc0[r];
      ldsM[ii * 65 + 32 + jj]         = acc1[r];
    } else if (wave == 2) {
      ldsM[(32 + ii) * 65 + jj]       = acc0[r];
      ldsM[(32 + ii) * 65 + 32 + jj]  = acc1[r];
    } else {
      ldsS[(32 + ii) * 65 + 32 + jj]  = acc0[r];
    }
  }
  __syncthreads();
  float* wsS = ws + ((size_t)(c * 32 + b) * 2) * 4096;
  float* wsM = wsS + 4096;
  #pragma unroll
  for (int k = 0; k < 16; ++k) {
    const int e = tid + 256 * k;
    const int i = e >> 6, j = e & 63;
    const float sv = (i >= 32 && j < 32) ? ldsS[j * 65 + i] : ldsS[i * 65 + j];
    wsS[e] = sv;                                    // symmetric mirror
    wsM[e] = ldsM[i * 65 + j] - ldsM[j * 65 + i];   // antisymmetrize
  }
}

// Sum CHUNKS chunk-partials, scale by 1/S. out = real[32][64][64] ++ imag[...].
template<int CHUNKS>
__global__ __launch_bounds__(256) void gram_reduce(
    const float4* __restrict__ ws, float4* __restrict__ out)
{
  const int o = blockIdx.x * 256 + threadIdx.x;   // 65536 float4s
  const int kind = o >> 15;
  const int rem  = o & 32767;
  const int b    = rem >> 10;
  const int e    = rem & 1023;
  const float inv = 1.0f / (float)SEQ;
  float sx = 0.f, sy = 0.f, sz = 0.f, sw = 0.f;
  #pragma unroll
  for (int c = 0; c < CHUNKS; ++c) {
    float4 v = ws[((size_t)(c * 32 + b) * 2 + kind) * 1024 + e];
    sx += v.x; sy += v.y; sz += v.z; sw += v.w;
  }
  float4 r; r.x = sx * inv; r.y = sy * inv; r.z = sz * inv; r.w = sw * inv;
  out[o] = r;
}

extern "C" void kernel_launch(void* const* d_in, const int* in_sizes, int n_in,
                              void* d_out, int out_size, void* d_ws, size_t ws_size,
                              hipStream_t stream) {
  const float* R = (const float*)d_in[0];
  const float* I = (const float*)d_in[1];
  float* out = (float*)d_out;
  float* ws  = (float*)d_ws;

  const size_t need32 = (size_t)32 * 32 * 2 * 4096 * 4;   // 33.6 MB
  if (ws_size >= need32) {
    gram_partial<32><<<BATCH * 32, 256, 0, stream>>>(R, I, ws);
    gram_reduce<32><<<256, 256, 0, stream>>>((const float4*)ws, (float4*)out);
  } else {
    gram_partial<16><<<BATCH * 16, 256, 0, stream>>>(R, I, ws);
    gram_reduce<16><<<256, 256, 0, stream>>>((const float4*)ws, (float4*)out);
  }
}

// Round 5
// 165.814 us; speedup vs baseline: 1.0367x; 1.0149x over previous
//
#include <hip/hip_runtime.h>

// ComplexMixture: B=32, S=8192, D=64, fp32 in/out.
// out_real = (R^T R + I^T I)/S ; out_imag = (R^T I - (R^T I)^T)/S
// R5: wave-private global_load_lds double-buffer pipeline, ZERO barriers in
// the main loop. Each wave owns a disjoint s-slice + private LDS buffers,
// computes all 7 output quads (S sym: 3, M: 4); quads summed across waves
// once in the epilogue. Split-K partials in ws + reduce kernel.

#define BATCH  32
#define SEQ    8192
#define DD     64
#define CHUNKS 16
#define SCHUNK (SEQ / CHUNKS)   // 512
#define ROUNDS (SCHUNK / 64)    // 8 (4 waves x 16 s per round)

typedef __bf16 bf16x8 __attribute__((ext_vector_type(8)));
typedef float  f32x16 __attribute__((ext_vector_type(16)));

#define GLD_LDS16(gp, lp) \
  __builtin_amdgcn_global_load_lds( \
      (const __attribute__((address_space(1))) void*)(gp), \
      (__attribute__((address_space(3))) void*)(lp), 16, 0, 0)

__device__ __forceinline__ unsigned bf16pk(float a, float b) {
  unsigned ua = __builtin_bit_cast(unsigned, a);
  unsigned ub = __builtin_bit_cast(unsigned, b);
  ua = (ua + 0x7fffu + ((ua >> 16) & 1u)) >> 16;   // RNE to bf16
  ub = (ub + 0x7fffu + ((ub >> 16) & 1u)) >> 16;
  return (ua & 0xffffu) | (ub << 16);
}

// Read 8 floats at stride 64 (one fragment's k-run), pack to bf16x8.
__device__ __forceinline__ bf16x8 ldsfrag(const float* p) {
  float f0 = p[0*64], f1 = p[1*64], f2 = p[2*64], f3 = p[3*64];
  float f4 = p[4*64], f5 = p[5*64], f6 = p[6*64], f7 = p[7*64];
  uint4 q;
  q.x = bf16pk(f0, f1); q.y = bf16pk(f2, f3);
  q.z = bf16pk(f4, f5); q.w = bf16pk(f6, f7);
  return __builtin_bit_cast(bf16x8, q);
}

#define MFMA(a, b, c) __builtin_amdgcn_mfma_f32_32x32x16_bf16((a), (b), (c), 0, 0, 0)

// LDS: 4 waves x 2 buffers x 2048 floats (buffer = R[16][64] ++ I[16][64])
//      = 16384 floats = 64 KB. Epilogue reuses [0..8320) as S/M 64x65 mats.
__global__ __launch_bounds__(256, 2) void gram_partial(
    const float* __restrict__ R, const float* __restrict__ I,
    float* __restrict__ ws)
{
  __shared__ float lds[16384];
  const int tid  = threadIdx.x;
  const int wave = tid >> 6;
  const int lane = tid & 63;
  const int l31  = lane & 31;
  const int lhi  = lane >> 5;
  const int b = blockIdx.x & 31;
  const int c = blockIdx.x >> 5;          // 0..15

  float* myb = lds + wave * 4096;         // wave-private 16 KB
  const size_t g0 = (size_t)b * (SEQ * DD) + (size_t)(c * SCHUNK + wave * 16) * DD;
  const float* gR = R + g0;
  const float* gI = I + g0;

  f32x16 aS0 = {}, aS1 = {}, aS2 = {};            // S(0,0) S(0,32) S(32,32)
  f32x16 aM0 = {}, aM1 = {}, aM2 = {}, aM3 = {};  // M(0,0) M(0,32) M(32,0) M(32,32)

  auto ISSUE = [&](int rnd, int p) {
    const float* r = gR + (size_t)rnd * (64 * DD);
    const float* i = gI + (size_t)rnd * (64 * DD);
    float* d = myb + p * 2048;
    #pragma unroll
    for (int t = 0; t < 4; ++t) {
      GLD_LDS16(r + t * 256 + lane * 4, d + t * 256);          // 4 s-rows, 1 KB
      GLD_LDS16(i + t * 256 + lane * 4, d + 1024 + t * 256);
    }
  };

  ISSUE(0, 0);
  #pragma unroll
  for (int r = 0; r < ROUNDS; ++r) {
    const int p = r & 1;
    if (r + 1 < ROUNDS) {
      ISSUE(r + 1, p ^ 1);
      asm volatile("s_waitcnt vmcnt(8)" ::: "memory");  // tile r done; prefetch in flight
    } else {
      asm volatile("s_waitcnt vmcnt(0)" ::: "memory");
    }
    const float* pR = myb + p * 2048 + (lhi * 8) * 64 + l31;
    const float* pI = pR + 1024;
    bf16x8 r0  = ldsfrag(pR),      r32 = ldsfrag(pR + 32);
    bf16x8 i0  = ldsfrag(pI),      i32 = ldsfrag(pI + 32);
    aS0 = MFMA(r0,  r0,  aS0);  aS0 = MFMA(i0,  i0,  aS0);
    aS1 = MFMA(r0,  r32, aS1);  aS1 = MFMA(i0,  i32, aS1);
    aS2 = MFMA(r32, r32, aS2);  aS2 = MFMA(i32, i32, aS2);
    aM0 = MFMA(r0,  i0,  aM0);
    aM1 = MFMA(r0,  i32, aM1);
    aM2 = MFMA(r32, i0,  aM2);
    aM3 = MFMA(r32, i32, aM3);
  }

  // ---- epilogue: sum wave quads in padded LDS, emit block partials ----
  __syncthreads();                        // all waves done with buffers
  float* Sp = lds;                        // 64 x 65
  float* Mp = lds + 4160;                 // 64 x 65
  for (int e = tid; e < 8320; e += 256) lds[e] = 0.0f;
  __syncthreads();
  #pragma unroll 1
  for (int w = 0; w < 4; ++w) {
    if (wave == w) {
      #pragma unroll
      for (int r = 0; r < 16; ++r) {
        const int ii = (r & 3) + 8 * (r >> 2) + 4 * lhi;
        const int jj = l31;
        Sp[ii * 65 + jj]              += aS0[r];
        Sp[ii * 65 + 32 + jj]         += aS1[r];
        Sp[(32 + ii) * 65 + 32 + jj]  += aS2[r];
        Mp[ii * 65 + jj]              += aM0[r];
        Mp[ii * 65 + 32 + jj]         += aM1[r];
        Mp[(32 + ii) * 65 + jj]       += aM2[r];
        Mp[(32 + ii) * 65 + 32 + jj]  += aM3[r];
      }
    }
    __syncthreads();
  }
  float* wsS = ws + ((size_t)(c * 32 + b) * 2) * 4096;
  float* wsM = wsS + 4096;
  #pragma unroll
  for (int k = 0; k < 16; ++k) {
    const int e = tid + 256 * k;
    const int i = e >> 6, j = e & 63;
    const float sv = (i >= 32 && j < 32) ? Sp[j * 65 + i] : Sp[i * 65 + j];
    wsS[e] = sv;                                  // symmetric mirror
    wsM[e] = Mp[i * 65 + j] - Mp[j * 65 + i];     // antisymmetrize
  }
}

// Sum CHUNKS chunk-partials, scale by 1/S. out = real[32][64][64] ++ imag[...].
__global__ __launch_bounds__(256) void gram_reduce(
    const float4* __restrict__ ws, float4* __restrict__ out)
{
  const int o = blockIdx.x * 256 + threadIdx.x;   // 65536 float4s
  const int kind = o >> 15;
  const int rem  = o & 32767;
  const int b    = rem >> 10;
  const int e    = rem & 1023;
  const float inv = 1.0f / (float)SEQ;
  float sx = 0.f, sy = 0.f, sz = 0.f, sw = 0.f;
  #pragma unroll
  for (int c = 0; c < CHUNKS; ++c) {
    float4 v = ws[((size_t)(c * 32 + b) * 2 + kind) * 1024 + e];
    sx += v.x; sy += v.y; sz += v.z; sw += v.w;
  }
  float4 r; r.x = sx * inv; r.y = sy * inv; r.z = sz * inv; r.w = sw * inv;
  out[o] = r;
}

extern "C" void kernel_launch(void* const* d_in, const int* in_sizes, int n_in,
                              void* d_out, int out_size, void* d_ws, size_t ws_size,
                              hipStream_t stream) {
  const float* R = (const float*)d_in[0];
  const float* I = (const float*)d_in[1];
  float* out = (float*)d_out;
  float* ws  = (float*)d_ws;   // 512 * 8192 * 4 B = 16.8 MB (R1 proved this fits)

  gram_partial<<<BATCH * CHUNKS, 256, 0, stream>>>(R, I, ws);
  gram_reduce<<<256, 256, 0, stream>>>((const float4*)ws, (float4*)out);
}